// Round 13
// baseline (4334.502 us; speedup 1.0000x reference)
//
#include <hip/hip_runtime.h>

#define NN   2048
#define NBLK 256
#define TPB  512
#define CPB  8          // columns per block, one 64-lane wave per column
#define SENT 1.0e30f    // finite "infinity" sentinel (fast-math-proof)

typedef unsigned long long u64;

struct BFWS {
  u64 pub[2][NN];    // (tag<<32)|fp32bits, double-buffered by round parity
  u64 cyc[NBLK];     // (tag NN<<32)|viol  for the negative-cycle gather
};

__device__ __forceinline__ u64 ld64(u64* p) {
  return __hip_atomic_load(p, __ATOMIC_RELAXED, __HIP_MEMORY_SCOPE_AGENT);
}
__device__ __forceinline__ void st64(u64* p, u64 v) {
  __hip_atomic_store(p, v, __ATOMIC_RELAXED, __HIP_MEMORY_SCOPE_AGENT);
}

// Full-wave (64-lane) min via 6 DPP ops, result valid in LANE 63.
// Pure VALU (~40 cy) vs 6 serial ds_bpermute (~250 cy) for __shfl_xor.
__device__ __forceinline__ float wave_min64_dpp(float x) {
  int v = __float_as_int(x);
  #define BF_STAGE(ctrl)                                                   \
    { int tdpp = __builtin_amdgcn_update_dpp(v, v, ctrl, 0xf, 0xf, false); \
      v = __float_as_int(fminf(__int_as_float(v), __int_as_float(tdpp))); }
  BF_STAGE(0x111)  // row_shr:1
  BF_STAGE(0x112)  // row_shr:2
  BF_STAGE(0x114)  // row_shr:4
  BF_STAGE(0x118)  // row_shr:8
  BF_STAGE(0x142)  // row_bcast:15
  BF_STAGE(0x143)  // row_bcast:31
  #undef BF_STAGE
  return __int_as_float(v);
}

__global__ void bf_init(BFWS* ws) {
  int t = threadIdx.x;
  if (t < NBLK) ws->cyc[t] = 0ull;   // tag 0: never matches (rounds are >=1)
}

__global__ void __launch_bounds__(TPB, 1)
bf_main(const float* __restrict__ A, const int* __restrict__ srcp,
        float* __restrict__ dist, float* __restrict__ pred,
        float* __restrict__ flagout, BFWS* ws) {
  const int tid = threadIdx.x;
  const int b   = blockIdx.x;
  const int c   = tid >> 6;       // column within block (0..7), one wave each
  const int s   = tid & 63;       // lane within the column's wave
  const int col = b * CPB + c;
  const int src = srcp[0];

  __shared__ __align__(16) float d_lds[2][NN];   // double-buffered d vector
  __shared__ int bflag;

  // ---- adjacency slice into registers: a[4k+m] = A[i][col], i = 4(s+64k)+m ----
  float a[32];
  #pragma unroll
  for (int k = 0; k < 8; ++k) {
    #pragma unroll
    for (int m = 0; m < 4; ++m) {
      int i = 4 * (s + 64 * k) + m;
      a[4 * k + m] = A[(size_t)i * NN + col];
    }
  }

  // ---- d0 into LDS buffer 0 (round 1 reads buf[0]) ----
  #pragma unroll
  for (int h = 0; h < 4; ++h) {
    int e = h * TPB + tid;
    d_lds[0][e] = (e == src) ? 0.f : SENT;
  }
  if (s == 0) {
    dist[(size_t)col * NN] = (col == src) ? 0.f : SENT;
    pred[(size_t)col * NN] = 0.f;
  }
  __syncthreads();

  for (int t = 1; t <= NN - 1; ++t) {
    if (t > 1) {
      // ---- poll+stage round t-1: 4 CONTIGUOUS tagged words per thread ----
      u64* pb = ws->pub[(t - 1) & 1] + 4 * tid;
      const unsigned want = (unsigned)(t - 1);
      u64 v[4];
      unsigned got = 0;
      while (got != 0xFu) {
        #pragma unroll
        for (int h = 0; h < 4; ++h)
          if (!((got >> h) & 1)) v[h] = ld64(pb + h);
        #pragma unroll
        for (int h = 0; h < 4; ++h)
          if (!((got >> h) & 1) && (unsigned)(v[h] >> 32) == want) got |= 1u << h;
        if (got != 0xFu) __builtin_amdgcn_s_sleep(1);
      }
      // contiguous stage: one 16B LDS write
      float4 f;
      f.x = __uint_as_float((unsigned)v[0]);
      f.y = __uint_as_float((unsigned)v[1]);
      f.z = __uint_as_float((unsigned)v[2]);
      f.w = __uint_as_float((unsigned)v[3]);
      *reinterpret_cast<float4*>(&d_lds[(t - 1) & 1][4 * tid]) = f;
      __syncthreads();   // single barrier per round (buffer-safety by parity)
    }

    // ---- min-plus over this thread's 32 i's, 4 independent chains ----
    float bv0 = 2.f * SENT, bv1 = 2.f * SENT, bv2 = 2.f * SENT, bv3 = 2.f * SENT;
    int   bi0 = 0,          bi1 = 1,          bi2 = 2,          bi3 = 3;
    const float4* dq4 = reinterpret_cast<const float4*>(d_lds[(t - 1) & 1]);
    #pragma unroll
    for (int k = 0; k < 8; ++k) {
      float4 dq = dq4[s + 64 * k];
      int base = 4 * (s + 64 * k);
      float c0 = dq.x + a[4 * k + 0];
      float c1 = dq.y + a[4 * k + 1];
      float c2 = dq.z + a[4 * k + 2];
      float c3 = dq.w + a[4 * k + 3];
      if (c0 < bv0) { bv0 = c0; bi0 = base + 0; }
      if (c1 < bv1) { bv1 = c1; bi1 = base + 1; }
      if (c2 < bv2) { bv2 = c2; bi2 = base + 2; }
      if (c3 < bv3) { bv3 = c3; bi3 = base + 3; }
    }

    // ---- FAST PATH: DPP value-only reduce -> publish from lane 63 ASAP ----
    float mv = wave_min64_dpp(fminf(fminf(bv0, bv1), fminf(bv2, bv3)));
    if (s == 63)
      st64(&ws->pub[t & 1][col], ((u64)(unsigned)t << 32) | (u64)__float_as_uint(mv));

    // ---- SLOW PATH (off critical path): argmin with first-index tie-break ----
    float bv = bv0; int bi = bi0;
    if (bv1 < bv || (bv1 == bv && bi1 < bi)) { bv = bv1; bi = bi1; }
    if (bv2 < bv || (bv2 == bv && bi2 < bi)) { bv = bv2; bi = bi2; }
    if (bv3 < bv || (bv3 == bv && bi3 < bi)) { bv = bv3; bi = bi3; }
    #pragma unroll
    for (int off = 32; off; off >>= 1) {
      float ov = __shfl_xor(bv, off, 64);
      int   oi = __shfl_xor(bi, off, 64);
      if (ov < bv || (ov == bv && oi < bi)) { bv = ov; bi = oi; }
    }
    if (s == 1) {
      dist[(size_t)col * NN + t] = bv;
      pred[(size_t)col * NN + t] = (float)bi;
    }
  }

  // ---- negative-cycle check on P_{NN-1} (slot (NN-1)&1 = 1) ----
  {
    u64* pb = ws->pub[(NN - 1) & 1] + 4 * tid;
    const unsigned want = (unsigned)(NN - 1);
    u64 v[4];
    unsigned got = 0;
    while (got != 0xFu) {
      #pragma unroll
      for (int h = 0; h < 4; ++h)
        if (!((got >> h) & 1)) v[h] = ld64(pb + h);
      #pragma unroll
      for (int h = 0; h < 4; ++h)
        if (!((got >> h) & 1) && (unsigned)(v[h] >> 32) == want) got |= 1u << h;
      if (got != 0xFu) __builtin_amdgcn_s_sleep(1);
    }
    float4 f;
    f.x = __uint_as_float((unsigned)v[0]);
    f.y = __uint_as_float((unsigned)v[1]);
    f.z = __uint_as_float((unsigned)v[2]);
    f.w = __uint_as_float((unsigned)v[3]);
    *reinterpret_cast<float4*>(&d_lds[1][4 * tid]) = f;
    if (tid == 0) bflag = 0;
    __syncthreads();

    float dj = d_lds[1][col];
    int viol = 0;
    const float4* dq4 = reinterpret_cast<const float4*>(d_lds[1]);
    #pragma unroll
    for (int k = 0; k < 8; ++k) {
      float4 dq = dq4[s + 64 * k];
      viol |= (dq.x + a[4 * k + 0] < dj);
      viol |= (dq.y + a[4 * k + 1] < dj);
      viol |= (dq.z + a[4 * k + 2] < dj);
      viol |= (dq.w + a[4 * k + 3] < dj);
    }
    if (viol) bflag = 1;      // benign same-value race within block
    __syncthreads();
    if (tid == 0)
      st64(&ws->cyc[b], ((u64)(unsigned)NN << 32) | (u64)(unsigned)bflag);
  }

  // ---- block 0 gathers the 256 tagged viol bits and writes the flag ----
  if (b == 0) {
    int myv = 0;
    if (tid < NBLK) {
      u64 w;
      do {
        w = ld64(&ws->cyc[tid]);
        if ((unsigned)(w >> 32) == (unsigned)NN) break;
        __builtin_amdgcn_s_sleep(1);
      } while (true);
      myv = (int)((unsigned)w & 1u);
    }
    if (tid == 0) bflag = 0;
    __syncthreads();
    if (myv) bflag = 1;       // benign same-value race
    __syncthreads();
    if (tid == 0) flagout[0] = bflag ? 1.f : 0.f;
  }
}

extern "C" void kernel_launch(void* const* d_in, const int* in_sizes, int n_in,
                              void* d_out, int out_size, void* d_ws, size_t ws_size,
                              hipStream_t stream) {
  (void)in_sizes; (void)n_in; (void)out_size; (void)ws_size;
  const float* A    = (const float*)d_in[0];
  const int*   srcp = (const int*)d_in[1];
  float* dist    = (float*)d_out;
  float* pred    = dist + (size_t)NN * NN;
  float* flagout = dist + (size_t)2 * NN * NN;
  BFWS*  ws      = (BFWS*)d_ws;

  bf_init<<<1, 256, 0, stream>>>(ws);
  bf_main<<<dim3(NBLK), dim3(TPB), 0, stream>>>(A, srcp, dist, pred, flagout, ws);
}